// Round 1
// 702.529 us; speedup vs baseline: 1.1261x; 1.1261x over previous
//
#include <hip/hip_runtime.h>

// Problem constants: B=4096, F=16, H=1280, N=8, R=64, TAU=1
// C = F*H = 20480 flattened feature dim; per-row f32 = 80 KB.
#define EPSF 1e-12f

typedef __bf16 bf16x8 __attribute__((ext_vector_type(8)));
typedef float  f32x4  __attribute__((ext_vector_type(4)));

// f32 -> bf16 round-to-nearest-even (bit trick; inputs are finite)
static __device__ __forceinline__ unsigned short f2b(float f) {
  unsigned int u = __float_as_uint(f);
  u += 0x7fffu + ((u >> 16) & 1u);
  return (unsigned short)(u >> 16);
}

static __device__ __forceinline__ bf16x8 as_bf(uint4 v) {
  union { uint4 u; bf16x8 b; } c; c.u = v; return c.b;
}

// ---- prep: convert down_w / up_w to bf16 in MFMA *fragment order* ----
// dw frag layout: [(e*4+rt)*40+s][lane][8] with value dw[e][rt*16+(lane&15)][s*32+(lane>>4)*8+j]
// uw frag layout: [(e*80+t)*2+s2][lane][8] with value uw[e][t*16+(lane&15)][s2*32+(lane>>4)*8+j]
// => every MFMA B-operand load in k2 is a fully coalesced 1024B dwordx4 wave-load.
__global__ __launch_bounds__(256) void prep_cvt(const float4* __restrict__ dw4,
                                                const float4* __restrict__ uw4,
                                                ushort4* __restrict__ dwb4,
                                                ushort4* __restrict__ uwb4) {
  const int o = blockIdx.x * 256 + threadIdx.x;   // [0, 163840) ushort4 units per tensor
  const int e = o / 20480, o1 = o - e * 20480;
  {
    const int rt = o1 / 5120, o2 = o1 - rt * 5120;
    const int s = o2 >> 7, r2 = o2 & 127;
    const int ln = r2 >> 1, j0 = (r2 & 1) << 2;
    const int src = (rt * 16 + (ln & 15)) * 1280 + (s << 5) + ((ln >> 4) << 3) + j0;
    float4 v = dw4[(e * 81920 + src) >> 2];
    ushort4 t; t.x = f2b(v.x); t.y = f2b(v.y); t.z = f2b(v.z); t.w = f2b(v.w);
    dwb4[o] = t;
  }
  {
    const int tt = o1 >> 8, o3 = o1 & 255;
    const int s2 = o3 >> 7, r2 = o3 & 127;
    const int ln = r2 >> 1, j0 = (r2 & 1) << 2;
    const int src = (tt * 16 + (ln & 15)) * 64 + (s2 << 5) + ((ln >> 4) << 3) + j0;
    float4 v = uw4[(e * 81920 + src) >> 2];
    ushort4 t; t.x = f2b(v.x); t.y = f2b(v.y); t.z = f2b(v.z); t.w = f2b(v.w);
    uwb4[o] = t;
  }
}

// ---- K1: gating. 1024 blocks x 256 thr; block handles 4 rows (1 per wave).
// gate_w is staged chunk-by-chunk into LDS ONCE per block and reused by all 4 rows
// (kills the per-b 640KB gate_w re-read of the old fused kernel). Gate row norms are
// accumulated during staging (free), so no separate norm kernel / dependency.
__global__ __launch_bounds__(256) void k1_gate(const float* __restrict__ x,
                                               const float* __restrict__ u,
                                               const float* __restrict__ gate_w,
                                               const float* __restrict__ sigma_p,
                                               int* __restrict__ sel) {
  __shared__ float gwch[8 * 1280];   // 40960 B exactly -> 4 blocks/CU
  const int tid = threadIdx.x, lane = tid & 63, w = tid >> 6;
  const int row = blockIdx.x * 4 + w;
  const float4* x4 = (const float4*)x + (size_t)row * 5120;
  const float4* gw4 = (const float4*)gate_w;
  float4* gwch4 = (float4*)gwch;

  float ss = 0.f;
  float dot[8];
#pragma unroll
  for (int n = 0; n < 8; ++n) dot[n] = 0.f;
  float gws0 = 0.f, gws1 = 0.f;   // sumsq of gate rows w and w+4

  for (int ch = 0; ch < 16; ++ch) {
    // stage: wave w stages expert rows w and w+4 (10 float4 per lane, coalesced)
    float4 gv[2][5];
#pragma unroll
    for (int rr = 0; rr < 2; ++rr) {
      const int n = w + 4 * rr;
#pragma unroll
      for (int p = 0; p < 5; ++p)
        gv[rr][p] = gw4[(size_t)n * 5120 + ch * 320 + p * 64 + lane];
    }
#pragma unroll
    for (int p = 0; p < 5; ++p) {
      float4 a = gv[0][p], b = gv[1][p];
      gwch4[(w)*320 + p * 64 + lane] = a;
      gwch4[(w + 4) * 320 + p * 64 + lane] = b;
      gws0 += a.x * a.x + a.y * a.y + a.z * a.z + a.w * a.w;
      gws1 += b.x * b.x + b.y * b.y + b.z * b.z + b.w * b.w;
    }
    __syncthreads();
    // compute: this wave's row vs all 8 experts (x loads issued back-to-back)
    float4 xv[5];
#pragma unroll
    for (int p = 0; p < 5; ++p) xv[p] = x4[ch * 320 + p * 64 + lane];
#pragma unroll
    for (int p = 0; p < 5; ++p) {
      float4 v = xv[p];
      ss += v.x * v.x + v.y * v.y + v.z * v.z + v.w * v.w;
#pragma unroll
      for (int n = 0; n < 8; ++n) {
        float4 g = gwch4[n * 320 + p * 64 + lane];
        dot[n] += v.x * g.x + v.y * g.y + v.z * g.z + v.w * g.w;
      }
    }
    __syncthreads();
  }

  // butterfly reduce (all lanes end with totals)
#pragma unroll
  for (int off = 32; off; off >>= 1) {
    ss += __shfl_xor(ss, off);
    gws0 += __shfl_xor(gws0, off);
    gws1 += __shfl_xor(gws1, off);
#pragma unroll
    for (int n = 0; n < 8; ++n) dot[n] += __shfl_xor(dot[n], off);
  }
  // exchange gate-row sumsq via the (now free) gwch scratch
  if (lane == 0) { gwch[w] = gws0; gwch[w + 4] = gws1; }
  __syncthreads();
  if (lane == 0) {
    const float sg = *sigma_p;
    const float inv_xn = 1.f / fmaxf(sqrtf(ss), EPSF);
    float best = -3.4e38f; int se = 0;
#pragma unroll
    for (int n = 0; n < 8; ++n) {
      const float gwi = 1.f / fmaxf(sqrtf(gwch[n]), EPSF);
      const float logit = sg * (dot[n] * inv_xn * gwi);
      const float uu = u[(size_t)row * 8 + n];
      const float g = -logf(-logf(uu + EPSF) + EPSF);   // gumbel; argmax(logits+g)==argmax(softmax)
      const float y = logit + g;
      if (y > best) { best = y; se = n; }                // first max wins, matches jnp.argmax
    }
    sel[row] = se;
  }
}

// ---- K2: LoRA. 4096 blocks x 256 thr (4 waves), one b per block.
// x[b] is staged into LDS as bf16 in fragment order: ushort idx = s*512 + lane*8 + j
// holding x[f=lane&15][k=s*32+(lane>>4)*8+j]. Both the stage ds_write_b128 and the
// phase-B ds_read_b128 are then linear (lane*16) => zero bank conflicts, no padding.
// LDS total 43.8 KB -> 3 blocks/CU; no gating phase, only 2 barriers.
__global__ __launch_bounds__(256) void k2_lora(const float* __restrict__ x,
                                               const int* __restrict__ sel,
                                               const unsigned short* __restrict__ dwb,
                                               const unsigned short* __restrict__ uwb,
                                               float* __restrict__ out) {
  __shared__ __align__(16) unsigned short xs[40 * 512];   // 40960 B, frag order
  __shared__ __align__(16) unsigned short mids[16 * 88];  // 2816 B ([f][r], LDA=88: 16B-aligned rows, ~2-way banks)
  const int b = blockIdx.x;
  const int tid = threadIdx.x, lane = tid & 63, w = tid >> 6;
  const int l16 = lane & 15, q = lane >> 4;
  const int e = sel[b];

  // stage x[b] -> bf16 fragment-order LDS. Per wave-load: 16 rows x 128B = full lines.
  const float4* xb4 = (const float4*)x + (size_t)b * 5120;
  const int c4b = l16 * 320 + q * 2;
#pragma unroll
  for (int t = 0; t < 10; ++t) {
    const int s = w + 4 * t;
    float4 v0 = xb4[c4b + s * 8];
    float4 v1 = xb4[c4b + s * 8 + 1];
    union { ushort4 h[2]; uint4 v; } pk;
    pk.h[0].x = f2b(v0.x); pk.h[0].y = f2b(v0.y); pk.h[0].z = f2b(v0.z); pk.h[0].w = f2b(v0.w);
    pk.h[1].x = f2b(v1.x); pk.h[1].y = f2b(v1.y); pk.h[1].z = f2b(v1.z); pk.h[1].w = f2b(v1.w);
    *(uint4*)&xs[s * 512 + lane * 8] = pk.v;   // linear 1024B per wave, conflict-free
  }
  __syncthreads();

  // phase B: mid[16,64] = x_b @ down_w[e]^T. Wave w owns r-tile w, full K=1280 (40 steps).
  const unsigned short* dwe = dwb + (size_t)(e * 4 + w) * 20480 + lane * 8;
  f32x4 acc = {0.f, 0.f, 0.f, 0.f};
#pragma unroll 8
  for (int s = 0; s < 40; ++s) {
    bf16x8 af = as_bf(*(const uint4*)&xs[s * 512 + lane * 8]);
    bf16x8 bf = as_bf(*(const uint4*)(dwe + (size_t)s * 512));
    acc = __builtin_amdgcn_mfma_f32_16x16x32_bf16(af, bf, acc, 0, 0, 0);
  }
  // D layout: col=lane&15 -> r within tile, row=(lane>>4)*4+j -> f
#pragma unroll
  for (int j = 0; j < 4; ++j)
    mids[(q * 4 + j) * 88 + w * 16 + l16] = f2b(acc[j]);
  __syncthreads();

  // phase C: out[16,1280] = mid @ up_w[e]^T, K=64. A-frags hoisted (read once).
  bf16x8 a0 = as_bf(*(const uint4*)&mids[l16 * 88 + q * 8]);        // k 0..31
  bf16x8 a1 = as_bf(*(const uint4*)&mids[l16 * 88 + 32 + q * 8]);   // k 32..63
  const unsigned short* uwe = uwb + (size_t)e * 81920 + lane * 8;
  float* outb = out + (size_t)b * 20480 + q * 4 * 1280 + l16;
#pragma unroll 2
  for (int t = w; t < 80; t += 4) {   // 20 h-tiles per wave
    const unsigned short* up = uwe + t * 1024;
    bf16x8 b0 = as_bf(*(const uint4*)up);
    bf16x8 b1 = as_bf(*(const uint4*)(up + 512));
    f32x4 o = {0.f, 0.f, 0.f, 0.f};
    o = __builtin_amdgcn_mfma_f32_16x16x32_bf16(a0, b0, o, 0, 0, 0);
    o = __builtin_amdgcn_mfma_f32_16x16x32_bf16(a1, b1, o, 0, 0, 0);
    float* op = outb + t * 16;
    op[0]    = o[0];
    op[1280] = o[1];
    op[2560] = o[2];
    op[3840] = o[3];
  }
}

extern "C" void kernel_launch(void* const* d_in, const int* in_sizes, int n_in,
                              void* d_out, int out_size, void* d_ws, size_t ws_size,
                              hipStream_t stream) {
  const float* x      = (const float*)d_in[0];  // [4096,16,1280] f32
  const float* u      = (const float*)d_in[1];  // [4096,8] f32
  const float* gate_w = (const float*)d_in[2];  // [8,20480] f32
  const float* sigma  = (const float*)d_in[3];  // scalar
  const float* down_w = (const float*)d_in[4];  // [8,64,1280] f32
  const float* up_w   = (const float*)d_in[5];  // [8,1280,64] f32
  float* out = (float*)d_out;                   // [4096,16,1280] f32

  // ws layout: [0,16384) sel int32[4096]; then down_w bf16-frag (1,310,720 B);
  // then up_w bf16-frag (1,310,720 B). Total 2,637,824 B.
  int* sel = (int*)d_ws;
  unsigned short* dwb = (unsigned short*)((char*)d_ws + 16384);
  unsigned short* uwb = dwb + 655360;

  prep_cvt<<<640, 256, 0, stream>>>((const float4*)down_w, (const float4*)up_w,
                                    (ushort4*)dwb, (ushort4*)uwb);
  k1_gate<<<1024, 256, 0, stream>>>(x, u, gate_w, sigma, sel);
  k2_lora<<<4096, 256, 0, stream>>>(x, sel, dwb, uwb, out);
}